// Round 5
// baseline (1449.146 us; speedup 1.0000x reference)
//
#include <hip/hip_runtime.h>
#include <hip/hip_fp16.h>

#define T_STEPS 512
#define BATCH   64
#define HID     512

// Scan W-row split (chunks of 8 f16 = one float4 = 4 VGPRs):
#define SR  36                  // register-resident chunks (144 VGPRs, pinned)
#define SL  14                  // LDS-resident chunks      (112 KB)
#define SSA 7                   // streamed batch A (L2)
#define SSB 7                   // streamed batch B (L2)   36+14+7+7 = 64

// Workspace layout: w_ih bf16 (512 KB) + w_hh f16 chunk-major-transposed (512 KB)
#define WIH_OFF   0u
#define WIH_BYTES (262144u * 2u)
#define WHHT_OFF  (WIH_OFF + WIH_BYTES)
#define WHHT_BYTES (262144u * 2u)
#define WS_FULL   (WHHT_OFF + WHHT_BYTES)

typedef _Float16 half2v  __attribute__((ext_vector_type(2)));
typedef short    short8  __attribute__((ext_vector_type(8)));
typedef float    f32x4   __attribute__((ext_vector_type(4)));
union F4H { float4 f; half2v h[4]; };

__device__ inline float dot2f(half2v a, half2v b, float c) {
    return __builtin_amdgcn_fdot2(a, b, c, false);
}
__device__ inline unsigned short f2bf(float f) {
    unsigned u = __builtin_bit_cast(unsigned, f);
    return (unsigned short)((u + 0x7FFFu + ((u >> 16) & 1u)) >> 16);
}

// ---------------------------------------------------------------------------
// w_ih fp32 -> bf16 (tiny, 0.5 MB)
// ---------------------------------------------------------------------------
__global__ __launch_bounds__(256) void cvt_bf16(const float* __restrict__ s,
                                                unsigned short* __restrict__ o) {
    const int i = (blockIdx.x * 256 + threadIdx.x) * 4;
    float4 v = *(const float4*)(s + i);
    ushort4 r = {f2bf(v.x), f2bf(v.y), f2bf(v.z), f2bf(v.w)};
    *(ushort4*)(o + i) = r;
}

// ---------------------------------------------------------------------------
// w_hh fp32 [row][col] -> f16 chunk-major: oT[(c*512 + r)*8 + k] = w[r*512+c*8+k]
// Writes coalesced (consecutive r -> consecutive 16B); reads L2/L3-absorbed.
// ---------------------------------------------------------------------------
__global__ __launch_bounds__(256) void cvt_whhT(const float* __restrict__ w,
                                                __half* __restrict__ o) {
    const int idx = blockIdx.x * 256 + threadIdx.x;   // 0..32767 = c*512 + r
    const int c = idx >> 9;
    const int r = idx & 511;
    float4 v0 = *(const float4*)(w + (size_t)r * 512 + c * 8);
    float4 v1 = *(const float4*)(w + (size_t)r * 512 + c * 8 + 4);
    __half2 p0; p0.x = __float2half(v0.x); p0.y = __float2half(v0.y);
    __half2 p1; p1.x = __float2half(v0.z); p1.y = __float2half(v0.w);
    __half2 p2; p2.x = __float2half(v1.x); p2.y = __float2half(v1.y);
    __half2 p3; p3.x = __float2half(v1.z); p3.y = __float2half(v1.w);
    __half2* dst = (__half2*)(o + (size_t)idx * 8);
    dst[0] = p0; dst[1] = p1; dst[2] = p2; dst[3] = p3;
}

// ---------------------------------------------------------------------------
// xproj via bf16 MFMA, x-conversion fused into A-staging (reads fp32 x).
// out[m][n] = sum_k x[m][k]*w_ih[n][k] + b_ih[n] + b_hh[n]
// ---------------------------------------------------------------------------
__global__ __launch_bounds__(256) void xproj_mfma2(
    const float* __restrict__ x,
    const unsigned short* __restrict__ w16,
    const float* __restrict__ b_ih, const float* __restrict__ b_hh,
    float* __restrict__ out)
{
    __shared__ __align__(16) unsigned short As[128][40];
    __shared__ __align__(16) unsigned short Bs[128][40];

    const int tid   = threadIdx.x;
    const int mBase = blockIdx.y * 128;
    const int nBase = blockIdx.x * 128;
    const int wave  = tid >> 6, lane = tid & 63;
    const int wy    = wave >> 1, wx = wave & 1;
    const int quad  = lane >> 4, l15 = lane & 15;
    const int lr    = tid >> 2;
    const int lk    = (tid & 3) * 8;

    f32x4 acc[4][4] = {};

    const size_t arow0 = (size_t)(mBase + lr) * 512 + lk;
    const size_t brow0 = (size_t)(nBase + lr) * 512 + lk;

    for (int k0 = 0; k0 < 512; k0 += 32) {
        float4 xa0 = *(const float4*)(x + arow0 + k0);
        float4 xa1 = *(const float4*)(x + arow0 + k0 + 4);
        float4 xb0 = *(const float4*)(x + arow0 + (size_t)64 * 512 + k0);
        float4 xb1 = *(const float4*)(x + arow0 + (size_t)64 * 512 + k0 + 4);
        int4 b0 = *(const int4*)(w16 + brow0 + k0);
        int4 b1 = *(const int4*)(w16 + brow0 + (size_t)64 * 512 + k0);
        __syncthreads();
        {
            ushort4 p0 = {f2bf(xa0.x), f2bf(xa0.y), f2bf(xa0.z), f2bf(xa0.w)};
            ushort4 p1 = {f2bf(xa1.x), f2bf(xa1.y), f2bf(xa1.z), f2bf(xa1.w)};
            ushort4 p2 = {f2bf(xb0.x), f2bf(xb0.y), f2bf(xb0.z), f2bf(xb0.w)};
            ushort4 p3 = {f2bf(xb1.x), f2bf(xb1.y), f2bf(xb1.z), f2bf(xb1.w)};
            *(ushort4*)&As[lr][lk]          = p0;
            *(ushort4*)&As[lr][lk + 4]      = p1;
            *(ushort4*)&As[lr + 64][lk]     = p2;
            *(ushort4*)&As[lr + 64][lk + 4] = p3;
        }
        *(int4*)&Bs[lr][lk]      = b0;
        *(int4*)&Bs[lr + 64][lk] = b1;
        __syncthreads();

        short8 af[4], bf[4];
#pragma unroll
        for (int mt = 0; mt < 4; ++mt)
            af[mt] = *(const short8*)&As[wy * 64 + mt * 16 + l15][quad * 8];
#pragma unroll
        for (int nt = 0; nt < 4; ++nt)
            bf[nt] = *(const short8*)&Bs[wx * 64 + nt * 16 + l15][quad * 8];
#pragma unroll
        for (int mt = 0; mt < 4; ++mt)
#pragma unroll
            for (int nt = 0; nt < 4; ++nt)
                acc[mt][nt] = __builtin_amdgcn_mfma_f32_16x16x32_bf16(
                    af[mt], bf[nt], acc[mt][nt], 0, 0, 0);
    }

    float bias[4]; int coln[4];
#pragma unroll
    for (int nt = 0; nt < 4; ++nt) {
        coln[nt] = nBase + wx * 64 + nt * 16 + l15;
        bias[nt] = b_ih[coln[nt]] + b_hh[coln[nt]];
    }
#pragma unroll
    for (int mt = 0; mt < 4; ++mt)
#pragma unroll
        for (int r = 0; r < 4; ++r) {
            const int row = mBase + wy * 64 + mt * 16 + quad * 4 + r;
#pragma unroll
            for (int nt = 0; nt < 4; ++nt)
                out[(size_t)row * 512 + coln[nt]] = acc[mt][nt][r] + bias[nt];
        }
}

// ---------------------------------------------------------------------------
// Fallback fp32 xproj (no-workspace path).
// ---------------------------------------------------------------------------
__global__ __launch_bounds__(256) void xproj_gemm(
    const float* __restrict__ x, const float* __restrict__ w_ih,
    const float* __restrict__ b_ih, const float* __restrict__ b_hh,
    float* __restrict__ out)
{
    __shared__ __align__(16) float As[16][68];
    __shared__ __align__(16) float Bs[16][68];

    const int tid   = threadIdx.x;
    const int tx    = tid & 15;
    const int ty    = tid >> 4;
    const int mBase = blockIdx.y * 64;
    const int nBase = blockIdx.x * 64;
    const int ldr   = tid >> 2;
    const int ldk   = (tid & 3) * 4;

    float acc[4][4] = {};
    const float* aptr = x    + (size_t)(mBase + ldr) * 512 + ldk;
    const float* bptr = w_ih + (size_t)(nBase + ldr) * 512 + ldk;

    for (int k0 = 0; k0 < 512; k0 += 16) {
        float4 av = *(const float4*)(aptr + k0);
        float4 bv = *(const float4*)(bptr + k0);
        __syncthreads();
        As[ldk + 0][ldr] = av.x; As[ldk + 1][ldr] = av.y;
        As[ldk + 2][ldr] = av.z; As[ldk + 3][ldr] = av.w;
        Bs[ldk + 0][ldr] = bv.x; Bs[ldk + 1][ldr] = bv.y;
        Bs[ldk + 2][ldr] = bv.z; Bs[ldk + 3][ldr] = bv.w;
        __syncthreads();
#pragma unroll
        for (int kk = 0; kk < 16; ++kk) {
            float4 a = *(const float4*)&As[kk][ty * 4];
            float4 b = *(const float4*)&Bs[kk][tx * 4];
            float ar[4] = {a.x, a.y, a.z, a.w};
            float br[4] = {b.x, b.y, b.z, b.w};
#pragma unroll
            for (int i = 0; i < 4; ++i)
#pragma unroll
                for (int j = 0; j < 4; ++j)
                    acc[i][j] = fmaf(ar[i], br[j], acc[i][j]);
        }
    }
    const int n0 = nBase + tx * 4;
    float bias[4];
#pragma unroll
    for (int j = 0; j < 4; ++j) bias[j] = b_ih[n0 + j] + b_hh[n0 + j];
#pragma unroll
    for (int i = 0; i < 4; ++i) {
        const int m = mBase + ty * 4 + i;
        float4 v = {acc[i][0] + bias[0], acc[i][1] + bias[1],
                    acc[i][2] + bias[2], acc[i][3] + bias[3]};
        *(float4*)(out + (size_t)m * 512 + n0) = v;
    }
}

// ---------------------------------------------------------------------------
// Scan v5: 36 chunks FORCED register-resident via amdgpu_num_vgpr(256) +
// per-iteration asm pins; 14 chunks LDS [c][j]; 14 streamed coalesced from
// chunk-major W^T. wT layout: chunk c, row j at wT + (c*512 + j)*8.
// ---------------------------------------------------------------------------
#define ACC4(WF, G) do {                                        \
    F4H hh_; hh_.f = *(const float4*)(hrow + (G) * 8);          \
    F4H ww_; ww_.f = (WF);                                      \
    a0 = dot2f(ww_.h[0], hh_.h[0], a0);                         \
    a1 = dot2f(ww_.h[1], hh_.h[1], a1);                         \
    a2 = dot2f(ww_.h[2], hh_.h[2], a2);                         \
    a3 = dot2f(ww_.h[3], hh_.h[3], a3); } while (0)

__global__ __launch_bounds__(512)
__attribute__((amdgpu_waves_per_eu(2, 2), amdgpu_num_vgpr(256)))
void rnn_scan5(const __half* __restrict__ wT, float* __restrict__ out)
{
    __shared__ __align__(16) float4 wlds[SL][HID];    // 112 KB ([c][j])
    __shared__ __align__(16) __half hbuf[2][HID];     // 2 KB -> 114 KB: 1 WG/CU

    const int b = blockIdx.x;
    const int j = threadIdx.x;

    // Register-resident chunks 0..35 (coalesced: consecutive j -> consecutive 16B)
    float4 wreg[SR];
#pragma unroll
    for (int c = 0; c < SR; ++c)
        wreg[c] = *(const float4*)(wT + ((size_t)c * HID + j) * 8);

    // LDS-resident chunks 36..49
#pragma unroll
    for (int c = 0; c < SL; ++c)
        wlds[c][j] = *(const float4*)(wT + ((size_t)(SR + c) * HID + j) * 8);

    hbuf[0][j] = __float2half(0.f);
    __syncthreads();

    float* outb = out + (size_t)b * HID + j;
    const size_t stride = (size_t)BATCH * HID;
    const __half* wstr = wT + ((size_t)(SR + SL) * HID + j) * 8;  // chunks 50..63
    const size_t cstride = (size_t)HID * 8;                       // 8 KB per chunk

    int cur = 0;
    float hn = 0.f;
    float xp_next = outb[0];

    for (int t = 0; t < T_STEPS; ++t) {
        // Pin: wreg is "modified" by empty asm each iteration -> compiler
        // cannot re-load it from memory; must carry 144 VGPRs across steps.
#pragma unroll
        for (int c = 0; c < SR; ++c)
            asm volatile("" : "+v"(wreg[c].x), "+v"(wreg[c].y),
                              "+v"(wreg[c].z), "+v"(wreg[c].w));

        const float xp = xp_next;
        const int tn = (t + 1 < T_STEPS) ? (t + 1) : t;
        xp_next = outb[(size_t)tn * stride];               // prefetch next xp

        const __half* hrow = hbuf[cur];

        // Issue streamed batch A (chunks 50..56), coalesced
        float4 wa[SSA];
#pragma unroll
        for (int c = 0; c < SSA; ++c)
            wa[c] = *(const float4*)(wstr + (size_t)c * cstride);

        float a0 = xp, a1 = 0.f, a2 = 0.f, a3 = 0.f;

        // Register part 1 (0..17) — hides batch-A latency
#pragma unroll
        for (int c = 0; c < 18; ++c) ACC4(wreg[c], c);

        // Consume batch A
#pragma unroll
        for (int c = 0; c < SSA; ++c)
            ACC4(wa[c], SR + SL + c);

        // Issue streamed batch B (chunks 57..63)
        float4 wb[SSB];
#pragma unroll
        for (int c = 0; c < SSB; ++c)
            wb[c] = *(const float4*)(wstr + (size_t)(SSA + c) * cstride);

        // Register part 2 (18..35) + LDS chunks (36..49) — hides batch-B
#pragma unroll
        for (int c = 18; c < SR; ++c) ACC4(wreg[c], c);
#pragma unroll
        for (int c = 0; c < SL; ++c) {
            float4 wf = wlds[c][j];
            ACC4(wf, SR + c);
        }

        // Consume batch B
#pragma unroll
        for (int c = 0; c < SSB; ++c)
            ACC4(wb[c], SR + SL + SSA + c);

        float s = (a0 + a1) + (a2 + a3);
        s = fminf(fmaxf(s, -15.f), 15.f);
        const float e = __expf(2.f * s);
        hn = (e - 1.f) * __builtin_amdgcn_rcpf(e + 1.f);

        outb[(size_t)t * stride] = hn;                     // in-place xp -> h_t
        hbuf[cur ^ 1][j] = __float2half(hn);
        __syncthreads();
        cur ^= 1;
    }
    out[(size_t)T_STEPS * stride + (size_t)b * HID + j] = hn;
}

// ---------------------------------------------------------------------------
// Last-resort fp32 scan (no workspace needed).
// ---------------------------------------------------------------------------
__global__ __launch_bounds__(512) void rnn_scan_f32(const float* __restrict__ w,
                                                    float* __restrict__ out)
{
    __shared__ __align__(16) __half hs[2][HID];
    const int b = blockIdx.x;
    const int j = threadIdx.x;

    hs[0][j] = __float2half(0.f);
    __syncthreads();

    const float* wrow32 = w + (size_t)j * HID;
    float* outb = out + (size_t)b * HID + j;
    int cur = 0;
    float hn = 0.f;

    for (int t = 0; t < T_STEPS; ++t) {
        float a0 = outb[(size_t)t * (BATCH * HID)];
        float a1 = 0.f, a2 = 0.f, a3 = 0.f;
#pragma unroll 4
        for (int k0 = 0; k0 < HID; k0 += 8) {
            float4 w0 = *(const float4*)(wrow32 + k0);
            float4 w1 = *(const float4*)(wrow32 + k0 + 4);
            F4H h; h.f = *(const float4*)(&hs[cur][k0]);
            float2 h0 = __half22float2(*(__half2*)&h.h[0]);
            float2 h1 = __half22float2(*(__half2*)&h.h[1]);
            float2 h2 = __half22float2(*(__half2*)&h.h[2]);
            float2 h3 = __half22float2(*(__half2*)&h.h[3]);
            a0 = fmaf(w0.x, h0.x, a0); a1 = fmaf(w0.y, h0.y, a1);
            a2 = fmaf(w0.z, h1.x, a2); a3 = fmaf(w0.w, h1.y, a3);
            a0 = fmaf(w1.x, h2.x, a0); a1 = fmaf(w1.y, h2.y, a1);
            a2 = fmaf(w1.z, h3.x, a2); a3 = fmaf(w1.w, h3.y, a3);
        }
        hn = tanhf((a0 + a1) + (a2 + a3));
        outb[(size_t)t * (BATCH * HID)] = hn;
        hs[cur ^ 1][j] = __float2half(hn);
        __syncthreads();
        cur ^= 1;
    }
    out[(size_t)T_STEPS * BATCH * HID + (size_t)b * HID + j] = hn;
}

// ---------------------------------------------------------------------------
extern "C" void kernel_launch(void* const* d_in, const int* in_sizes, int n_in,
                              void* d_out, int out_size, void* d_ws, size_t ws_size,
                              hipStream_t stream) {
    const float* x    = (const float*)d_in[0];
    const float* w_ih = (const float*)d_in[1];
    const float* w_hh = (const float*)d_in[2];
    const float* b_ih = (const float*)d_in[3];
    const float* b_hh = (const float*)d_in[4];
    float* out = (float*)d_out;

    char* ws = (char*)d_ws;
    if (ws_size >= (size_t)WS_FULL) {
        unsigned short* wih16 = (unsigned short*)(ws + WIH_OFF);
        __half*         whhT  = (__half*)(ws + WHHT_OFF);
        cvt_bf16<<<256, 256, 0, stream>>>(w_ih, wih16);
        cvt_whhT<<<128, 256, 0, stream>>>(w_hh, whhT);
        xproj_mfma2<<<dim3(4, 256), 256, 0, stream>>>(x, wih16, b_ih, b_hh, out);
        rnn_scan5<<<BATCH, HID, 0, stream>>>(whhT, out);
    } else {
        xproj_gemm<<<dim3(8, 512), 256, 0, stream>>>(x, w_ih, b_ih, b_hh, out);
        rnn_scan_f32<<<BATCH, HID, 0, stream>>>(w_hh, out);
    }
}